// Round 2
// baseline (255.564 us; speedup 1.0000x reference)
//
#include <hip/hip_runtime.h>

// PyramidLevel1Block: gather(cur_x by up_idx) ++ pre_x -> GEMM(192x128) -> BN -> ReLU
// B=4, M=65536, N=16384, C_pre=64, C_cur=128, C_in=192, D=128.
//
// Kernel 1: transpose+convert cur_x (B,128,N) fp32 -> curT (B,N,128) bf16 (d_ws)
//           so the per-row gather is 256 B contiguous instead of 128 x 64KB-strided lines.
// Kernel 2: 64 rows/block x 2 tiles, operand-SWAPPED MFMA (W as A-operand, X as B):
//           D = W^T·X^T puts 4 consecutive d per lane -> f32x4 epilogue stores
//           (8 dwordx4 vs 32 dword per tile/thread). Cross-tile register prefetch
//           (idx -> gather dependent chain + pre_x) hides global latency under
//           tile-0 compute (T14 async-STAGE: reg-loads survive __syncthreads).
// __launch_bounds__(256,2): don't force 3 waves/SIMD — the +32 prefetch VGPRs
//           must stay in registers (a spill would turn latency-hiding into
//           scratch traffic).

typedef short bhalf8 __attribute__((ext_vector_type(8)));
typedef float f32x4 __attribute__((ext_vector_type(4)));
typedef unsigned int u32x4 __attribute__((ext_vector_type(4)));

__device__ __forceinline__ short f2bf(float f) {
  // round-to-nearest-even float -> bf16 (finite inputs only)
  unsigned int u = __float_as_uint(f);
  unsigned int r = (u + 0x7fffu + ((u >> 16) & 1u)) >> 16;
  return (short)r;
}

// ---------------- Kernel 1: cur_x (B,128,16384) f32 -> curT (B,16384,128) bf16 ---
__global__ __launch_bounds__(256) void transpose_cur(const float* __restrict__ cur,
                                                     short* __restrict__ curT) {
  __shared__ float tile[128][65];  // +1 pad: conflict-free col reads
  const int b = blockIdx.y;
  const int n0 = blockIdx.x << 6;  // 64 n per block
  const float* src = cur + (size_t)b * 128 * 16384;
#pragma unroll
  for (int it = 0; it < 8; ++it) {
    int v = it * 256 + threadIdx.x;
    int cc = v >> 4;
    int nq = (v & 15) << 2;
    f32x4 f = __builtin_nontemporal_load(
        reinterpret_cast<const f32x4*>(&src[(size_t)cc * 16384 + n0 + nq]));
    tile[cc][nq + 0] = f[0];
    tile[cc][nq + 1] = f[1];
    tile[cc][nq + 2] = f[2];
    tile[cc][nq + 3] = f[3];
  }
  __syncthreads();
  short* dst = curT + ((size_t)b * 16384 + n0) * 128;
#pragma unroll
  for (int it = 0; it < 4; ++it) {
    int v = it * 256 + threadIdx.x;
    int nn = v >> 4;
    int c8 = (v & 15) << 3;
    bhalf8 pk;
#pragma unroll
    for (int j = 0; j < 8; ++j) pk[j] = f2bf(tile[c8 + j][nn]);
    *reinterpret_cast<bhalf8*>(&dst[(size_t)nn * 128 + c8]) = pk;
  }
}

// ---------------- Kernel 2: fused gather+GEMM+BN+ReLU -----------------------------
#define NBLK 2048  // row-groups = 4096 (64 rows each), 2 per block

__global__ __launch_bounds__(256, 2) void fused_gemm(
    const float* __restrict__ pre_x,  // (4, 64, 65536)
    const int* __restrict__ up_idx,   // (4, 65536)
    const float* __restrict__ w,      // (192, 128)
    const float* __restrict__ bias,   // (128)
    const float* __restrict__ gamma, const float* __restrict__ beta,
    const float* __restrict__ rmean, const float* __restrict__ rvar,
    const short* __restrict__ curT,  // (4, 16384, 128) bf16
    float* __restrict__ out)         // (4, 65536, 128) f32
{
  // x-tile: 64 rows x 192 k (bf16), row stride 200 shorts (400 B: 16B-aligned)
  __shared__ short x_lds[64 * 200];
  const int tid = threadIdx.x;
  const int lane = tid & 63;
  const int wv = tid >> 6;    // wave 0..3 -> d cols [32wv, 32wv+32)
  const int c = lane & 15;    // MFMA: A-row(d) / B-col(m) / C-col(m) index
  const int g = lane >> 4;    // MFMA quad: k-group (A/B), d-row group (C)
  const int mrow = tid >> 4;  // 0..15: staging row / idx row
  const int seg = tid & 15;   // 0..15: staging 16B segment / m-quad

  // W fragments in registers, used as MFMA *A* operand (operand-swapped):
  // bf[s][ct][j] = w[32s + 8g + j][32wv + 16ct + c]  (A row index = lane&15 = d)
  bhalf8 bf[6][2];
#pragma unroll
  for (int s = 0; s < 6; ++s)
#pragma unroll
    for (int ct = 0; ct < 2; ++ct) {
      const int col = 32 * wv + 16 * ct + c;
#pragma unroll
      for (int j = 0; j < 8; ++j)
        bf[s][ct][j] = f2bf(w[(32 * s + 8 * g + j) * 128 + col]);
    }

  // fold bias + BN: per-lane f32x4 over d = 32wv + 16ct + 4g + i
  f32x4 scale4[2], shift4[2];
#pragma unroll
  for (int ct = 0; ct < 2; ++ct) {
    const int d0 = 32 * wv + 16 * ct + 4 * g;
    f32x4 gm = *reinterpret_cast<const f32x4*>(&gamma[d0]);
    f32x4 rv = *reinterpret_cast<const f32x4*>(&rvar[d0]);
    f32x4 bs = *reinterpret_cast<const f32x4*>(&bias[d0]);
    f32x4 rm = *reinterpret_cast<const f32x4*>(&rmean[d0]);
    f32x4 bt = *reinterpret_cast<const f32x4*>(&beta[d0]);
#pragma unroll
    for (int i = 0; i < 4; ++i) {
      float sc = gm[i] * rsqrtf(rv[i] + 1e-5f);
      scale4[ct][i] = sc;
      shift4[ct][i] = (bs[i] - rm[i]) * sc + bt[i];
    }
  }

  const long r0a = ((long)blockIdx.x) << 6;          // tile 0 first row
  const long r0b = ((long)(blockIdx.x + NBLK)) << 6; // tile 1 first row
  const int ba = (int)(r0a >> 16), m0a = (int)(r0a & 65535);
  const int bb = (int)(r0b >> 16), m0b = (int)(r0b & 65535);

  // ---- prologue: indices for BOTH tiles (idx1 lands during tile-0 work),
  //                pre_x + gather globals for tile 0
  int idx0[4], idx1[4];
#pragma unroll
  for (int it = 0; it < 4; ++it) idx0[it] = up_idx[r0a + it * 16 + mrow];
#pragma unroll
  for (int it = 0; it < 4; ++it) idx1[it] = up_idx[r0b + it * 16 + mrow];

  f32x4 pre0[4];
  const float* pba = pre_x + (size_t)ba * 64 * 65536 + m0a;
#pragma unroll
  for (int it = 0; it < 4; ++it)
    pre0[it] = __builtin_nontemporal_load(reinterpret_cast<const f32x4*>(
        &pba[(size_t)(it * 16 + mrow) * 65536 + (seg << 2)]));
  u32x4 gat0[4];
#pragma unroll
  for (int it = 0; it < 4; ++it)
    gat0[it] = *reinterpret_cast<const u32x4*>(
        curT + ((size_t)ba * 16384 + idx0[it]) * 128 + seg * 8);

  // ---- stage tile 0 into LDS (regs -> LDS; compiler inserts vmcnt waits)
#define STAGE_LDS(pre, gat)                                                   \
  {                                                                           \
    _Pragma("unroll") for (int it = 0; it < 4; ++it) {                        \
      const int cc = it * 16 + mrow;                                          \
      const int mq = seg << 2;                                                \
      x_lds[(mq + 0) * 200 + cc] = f2bf(pre[it][0]);                          \
      x_lds[(mq + 1) * 200 + cc] = f2bf(pre[it][1]);                          \
      x_lds[(mq + 2) * 200 + cc] = f2bf(pre[it][2]);                          \
      x_lds[(mq + 3) * 200 + cc] = f2bf(pre[it][3]);                          \
    }                                                                         \
    _Pragma("unroll") for (int it = 0; it < 4; ++it) {                        \
      const int mm = it * 16 + mrow;                                          \
      *reinterpret_cast<u32x4*>(&x_lds[mm * 200 + 64 + seg * 8]) = gat[it];   \
    }                                                                         \
  }

  STAGE_LDS(pre0, gat0);

  // ---- prefetch tile 1 globals into registers; they stay in flight across
  //      the barrier and tile-0 compute (reg loads don't force vmcnt(0) drain)
  f32x4 pre1[4];
  const float* pbb = pre_x + (size_t)bb * 64 * 65536 + m0b;
#pragma unroll
  for (int it = 0; it < 4; ++it)
    pre1[it] = __builtin_nontemporal_load(reinterpret_cast<const f32x4*>(
        &pbb[(size_t)(it * 16 + mrow) * 65536 + (seg << 2)]));
  u32x4 gat1[4];
#pragma unroll
  for (int it = 0; it < 4; ++it)
    gat1[it] = *reinterpret_cast<const u32x4*>(
        curT + ((size_t)bb * 16384 + idx1[it]) * 128 + seg * 8);

  // compute one 64-row tile from LDS; operand-swapped MFMA:
  // D[d][m] = W^T X^T -> lane holds m = 16rt + c, d = 32wv + 16ct + 4g + i
  auto compute_tile = [&](long r0) {
#pragma unroll
    for (int rt = 0; rt < 4; ++rt) {
      bhalf8 a[6];
#pragma unroll
      for (int s = 0; s < 6; ++s)
        a[s] = *reinterpret_cast<const bhalf8*>(
            &x_lds[(16 * rt + c) * 200 + 32 * s + 8 * g]);
      f32x4 acc0 = {0.f, 0.f, 0.f, 0.f};
      f32x4 acc1 = {0.f, 0.f, 0.f, 0.f};
#pragma unroll
      for (int s = 0; s < 6; ++s) {
        acc0 = __builtin_amdgcn_mfma_f32_16x16x32_bf16(bf[s][0], a[s], acc0, 0, 0, 0);
        acc1 = __builtin_amdgcn_mfma_f32_16x16x32_bf16(bf[s][1], a[s], acc1, 0, 0, 0);
      }
      // epilogue: 4 consecutive d per lane -> two 16-B nontemporal stores
      float* ob = out + (size_t)(r0 + 16 * rt + c) * 128 + 32 * wv + 4 * g;
      f32x4 v0, v1;
#pragma unroll
      for (int i = 0; i < 4; ++i) {
        v0[i] = fmaxf(acc0[i] * scale4[0][i] + shift4[0][i], 0.f);
        v1[i] = fmaxf(acc1[i] * scale4[1][i] + shift4[1][i], 0.f);
      }
      __builtin_nontemporal_store(v0, reinterpret_cast<f32x4*>(ob));
      __builtin_nontemporal_store(v1, reinterpret_cast<f32x4*>(ob + 16));
    }
  };

  __syncthreads();
  compute_tile(r0a);
  __syncthreads();          // all waves done reading tile-0 LDS
  STAGE_LDS(pre1, gat1);    // vmcnt waits land here, mostly already satisfied
  __syncthreads();
  compute_tile(r0b);
}

extern "C" void kernel_launch(void* const* d_in, const int* in_sizes, int n_in,
                              void* d_out, int out_size, void* d_ws, size_t ws_size,
                              hipStream_t stream) {
  const float* pre_x = (const float*)d_in[0];
  const float* cur_x = (const float*)d_in[1];
  const int* up_idx = (const int*)d_in[2];
  const float* w = (const float*)d_in[3];
  const float* bias = (const float*)d_in[4];
  const float* gamma = (const float*)d_in[5];
  const float* beta = (const float*)d_in[6];
  const float* rmean = (const float*)d_in[7];
  const float* rvar = (const float*)d_in[8];
  float* out = (float*)d_out;
  short* curT = (short*)d_ws;  // (4, 16384, 128) bf16 = 16.8 MB

  hipLaunchKernelGGL(transpose_cur, dim3(256, 4), dim3(256), 0, stream, cur_x, curT);
  hipLaunchKernelGGL(fused_gemm, dim3(NBLK), dim3(256), 0, stream, pre_x, up_idx, w,
                     bias, gamma, beta, rmean, rvar, curT, out);
}